// Round 9
// baseline (1222.798 us; speedup 1.0000x reference)
//
#include <hip/hip_runtime.h>
#include <hip/hip_bf16.h>

#define EMBED 128
#define TSTEPS 128
#define NBATCH 32
#define VDIM 50257
#define VPAD 50304            // 786 groups * 64 cols
#define MROWS 4096            // NBATCH * TSTEPS
#define NGROUPS 786           // VPAD / 64
#define GEMM_X 256            // B-sweep split (3-4 groups per block)
#define NCHUNK 16             // t-chunks (8 steps = 256 rows each)
#define CONV_N4 ((VDIM * EMBED) / 4)          // 1608224 float4 elements
#define CONVB ((CONV_N4 + 255) / 256)         // 6283
#define GEMMB (GEMM_X * NCHUNK)               // 4096
#define NBLK (NBATCH + CONVB + GEMMB)         // 10411

// flag slots (stride 16 ints = 64B apart to avoid line contention):
//   chunk c ready counter  -> flags[c*16]        (target NBATCH)
//   conv done counter      -> flags[16*16]       (target CONVB)
//   slice done counter     -> flags[(17+y)*16]   (target GEMM_X)
#define FLAG_INTS ((17 + NCHUNK) * 16)

static constexpr float LOG2E = 1.4426950408889634f;
static constexpr float LN2   = 0.6931471805599453f;

__device__ __forceinline__ float fast_exp2(float x) {
#if __has_builtin(__builtin_amdgcn_exp2f)
    return __builtin_amdgcn_exp2f(x);
#else
    return exp2f(x);
#endif
}
__device__ __forceinline__ float fast_log2(float x) {
#if __has_builtin(__builtin_amdgcn_logf)
    return __builtin_amdgcn_logf(x);
#else
    return log2f(x);
#endif
}
__device__ __forceinline__ unsigned short f2bf_raw(float f) {
    __hip_bfloat16 h = __float2bfloat16(f);
    union { __hip_bfloat16 b; unsigned short u; } cvt;
    cvt.b = h;
    return cvt.u;
}
__device__ __forceinline__ float bf_raw2f(unsigned short u) {
    union { unsigned int u; float f; } cvt;
    cvt.u = ((unsigned int)u) << 16;
    return cvt.f;
}
__device__ __forceinline__ int agent_load(const int* p) {
    return __hip_atomic_load(p, __ATOMIC_RELAXED, __HIP_MEMORY_SCOPE_AGENT);
}
__device__ __forceinline__ float agent_loadf(const float* p) {
    return __hip_atomic_load(p, __ATOMIC_RELAXED, __HIP_MEMORY_SCOPE_AGENT);
}

typedef __attribute__((ext_vector_type(8))) short bfrag;
typedef __attribute__((ext_vector_type(4))) float f32x4;

// ---------------------------------------------------------------------------
// ONE fused kernel. Roles by blockIdx.x:
//  [0,32): sequential scan, one batch chain per block.  zsb is T-MAJOR
//    (row = t*32 + b) so a 256-row M-slice is complete every 8 steps; after
//    each 8-step chunk: __threadfence (release, cross-XCD writeback) + agent
//    atomicAdd on the chunk flag.  fp32 summation order ((zc+sA)+sB)+bt and
//    libm tanhf are bit-exact vs rounds 1/3/5-8 (round-4: the recurrence
//    amplifies 1e-6/step approximations to 0.2 absmax — don't perturb).
//  [32, 32+CONVB): convert Wv fp32->bf16 (+ zero pad rows), build ebt[j] =
//    exp2(bv[j]*log2e) (pad = 0), then release-fence + conv flag.
//  [32+CONVB, ...): 4096 GEMM blocks (R7's known-good 74us internals:
//    LDS-staged double-buffered 16KB B-tiles via global_load_lds w=16 with
//    XOR-16 swizzle, a[4][4] reg-resident A, 64 MFMA/barrier, VGPR ~110 ->
//    4 waves/SIMD; round-8 showed bigger per-wave tiles kill occupancy).
//    Each handles M-slice y (256 rows) x 3-4 B-groups; spins (s_sleep) on
//    conv + chunk-y flags with acquire fence before reads.  y is the slow
//    dispatch index -> earliest-gated blocks dispatch first; producers are
//    blocks 0..31 (first in grid, co-resident from t=0 -> no deadlock).
//    After the S atomics: release-fence + done-counter; the 256th block of
//    a slice computes the 256 outputs (fused tail: fp32 target dot from
//    bf16 zsb x fp32 Wv, S via agent atomic loads).
// ---------------------------------------------------------------------------
__global__ __launch_bounds__(256) void fused_kernel(const int* __restrict__ zi,
                                                    const int* __restrict__ yidx,
                                                    const float* __restrict__ latent,
                                                    const float* __restrict__ Wt,
                                                    const float* __restrict__ bt,
                                                    const float* __restrict__ Wv,
                                                    const float* __restrict__ bv,
                                                    unsigned short* __restrict__ zsb,
                                                    unsigned short* __restrict__ Wvb,
                                                    float* __restrict__ ebt,
                                                    float* __restrict__ S,
                                                    int* __restrict__ flags,
                                                    float* __restrict__ out) {
    __shared__ short ldsb[2][8192];          // gemm: 2 x 16 KB B tiles
    __shared__ float zbuf[2][EMBED];         // scan: ping-pong z
    __shared__ int   iswin;

    const int bx = blockIdx.x;

    // ================= scan blocks =================
    if (bx < NBATCH) {
        const int b = bx;
        const int e = threadIdx.x >> 1;     // output element 0..127
        const int h = threadIdx.x & 1;      // k-half

        float4 wrow[16];
        const float4* wt4 = reinterpret_cast<const float4*>(Wt + e * EMBED + h * 64);
#pragma unroll
        for (int i = 0; i < 16; i++) wrow[i] = wt4[i];
        const float bte = bt[e];

        if (h == 0) zbuf[0][e] = latent[zi[b] * EMBED + e];
        __syncthreads();

        int cur = 0;
        for (int t = 0; t < TSTEPS; t++) {
            const float zc = zbuf[cur][e];
            if (h == 0)                     // t-major row, bf16 * log2e
                zsb[((long)t * NBATCH + b) * EMBED + e] = f2bf_raw(zc * LOG2E);

            const float4* z4 = reinterpret_cast<const float4*>(&zbuf[cur][h * 64]);
            float4 acc = {0.f, 0.f, 0.f, 0.f};
#pragma unroll
            for (int i = 0; i < 16; i++) {
                float4 zv = z4[i];
                acc.x += zv.x * wrow[i].x;
                acc.y += zv.y * wrow[i].y;
                acc.z += zv.z * wrow[i].z;
                acc.w += zv.w * wrow[i].w;
            }
            float v = acc.x + acc.y + acc.z + acc.w;
            float p = __shfl_xor(v, 1);
            float sA = h ? p : v;
            float sB = h ? v : p;
            float znew = tanhf(((zc + sA) + sB) + bte);   // exact libm tanh
            if (h == 0) zbuf[cur ^ 1][e] = znew;
            __syncthreads();
            cur ^= 1;

            if ((t & 7) == 7) {             // chunk t>>3 rows all stored
                __threadfence();            // release (cross-XCD writeback)
                __syncthreads();
                if (threadIdx.x == 0)
                    atomicAdd(&flags[(t >> 3) * 16], 1);
            }
        }
        return;
    }

    // ================= conversion blocks =================
    if (bx < NBATCH + CONVB) {
        const int cb = bx - NBATCH;
        if (cb == 0) {                      // zero bf16 pad rows of Wvb
            const int base4 = (VDIM * EMBED) / 4;
            const int npad4 = ((VPAD - VDIM) * EMBED) / 4;
            for (int i = threadIdx.x; i < npad4; i += 256)
                reinterpret_cast<ushort4*>(Wvb)[base4 + i] = make_ushort4(0, 0, 0, 0);
        }
        const int idx = cb * 256 + threadIdx.x;
        if (idx < VPAD)                     // ebt = e^bv (pad -> 0)
            ebt[idx] = (idx < VDIM) ? fast_exp2(bv[idx] * LOG2E) : 0.f;
        if (idx < CONV_N4) {
            float4 v = reinterpret_cast<const float4*>(Wv)[idx];
            ushort4 o;
            o.x = f2bf_raw(v.x); o.y = f2bf_raw(v.y);
            o.z = f2bf_raw(v.z); o.w = f2bf_raw(v.w);
            reinterpret_cast<ushort4*>(Wvb)[idx] = o;
        }
        __threadfence();                    // release
        __syncthreads();
        if (threadIdx.x == 0) atomicAdd(&flags[16 * 16], 1);
        return;
    }

    // ================= gemm blocks =================
    const int gi = bx - NBATCH - CONVB;
    const int y  = gi >> 8;                 // M-slice (t-chunk), slow index
    const int x  = gi & 255;                // B-sweep slice

    // gate: conv done AND chunk y scanned (thread 0 spins, all sync after)
    if (threadIdx.x == 0) {
        int guard = 0;
        while (agent_load(&flags[16 * 16]) < CONVB && ++guard < (1 << 20))
            __builtin_amdgcn_s_sleep(16);
        guard = 0;
        while (agent_load(&flags[y * 16]) < NBATCH && ++guard < (1 << 20))
            __builtin_amdgcn_s_sleep(16);
    }
    __syncthreads();
    __threadfence();                        // acquire: invalidate stale cache

    const int lane  = threadIdx.x & 63;
    const int wave  = threadIdx.x >> 6;
    const int col16 = lane & 15;
    const int quad  = lane >> 4;
    const int mbase = y * 256 + wave * 64;

    // group range: 786 = 256*3 + 18
    const int g0 = x * 3 + min(x, 18);
    const int g1 = g0 + 3 + (x < 18 ? 1 : 0);

    // A fragments: 4 M-subtiles x 4 K-chunks, register resident
    bfrag a[4][4];
    const short* zss = reinterpret_cast<const short*>(zsb);
#pragma unroll
    for (int s = 0; s < 4; s++)
#pragma unroll
        for (int c = 0; c < 4; c++) {
            const short* p = zss + (long)(mbase + s * 16 + col16) * EMBED + c * 32 + quad * 8;
            a[s][c] = *reinterpret_cast<const bfrag*>(p);
        }

    float sums[16];
#pragma unroll
    for (int i = 0; i < 16; i++) sums[i] = 0.f;

    const short* wvs = reinterpret_cast<const short*>(Wvb);

    auto stage = [&](int buf, int g) {
#pragma unroll
        for (int j = 0; j < 4; j++) {
            const int r   = (wave * 4 + j) * 4 + quad;
            const int swz = col16 ^ (r & 15);          // XOR-16 granule swizzle
            const short* gp = wvs + (long)(g * 64 + r) * EMBED + swz * 8;
            __builtin_amdgcn_global_load_lds(
                (const __attribute__((address_space(1))) void*)gp,
                (__attribute__((address_space(3))) void*)&ldsb[buf][(wave * 4 + j) * 512],
                16, 0, 0);
        }
    };

    int cur = 0;
    stage(0, g0);

    const f32x4 dzero = {0.f, 0.f, 0.f, 0.f};

    for (int g = g0; g < g1; g++) {
        __syncthreads();
        if (g + 1 < g1) stage(cur ^ 1, g + 1);

        float ebl[4];                       // e^bias, issued early, used late
#pragma unroll
        for (int c = 0; c < 4; c++) ebl[c] = ebt[g * 64 + c * 16 + col16];

#pragma unroll
        for (int c = 0; c < 4; c++) {
            bfrag bf[4];
#pragma unroll
            for (int kc = 0; kc < 4; kc++)
                bf[kc] = *reinterpret_cast<const bfrag*>(
                    &ldsb[cur][(c * 16 + col16) * 128 + (((kc * 4 + quad) ^ col16) * 8)]);

            f32x4 d[4];
#pragma unroll
            for (int s = 0; s < 4; s++)
                d[s] = __builtin_amdgcn_mfma_f32_16x16x32_bf16(a[s][0], bf[0], dzero, 0, 0, 0);
#pragma unroll
            for (int kc = 1; kc < 4; kc++)
#pragma unroll
                for (int s = 0; s < 4; s++)
                    d[s] = __builtin_amdgcn_mfma_f32_16x16x32_bf16(a[s][kc], bf[kc], d[s], 0, 0, 0);

#pragma unroll
            for (int s = 0; s < 4; s++)
#pragma unroll
                for (int r = 0; r < 4; r++)
                    sums[s * 4 + r] = fmaf(fast_exp2(d[s][r]), ebl[c], sums[s * 4 + r]);
        }
        cur ^= 1;
    }

    // reduce over 16 columns, one atomic per row per block
#pragma unroll
    for (int s = 0; s < 4; s++) {
#pragma unroll
        for (int r = 0; r < 4; r++) {
            float v = sums[s * 4 + r];
            v += __shfl_xor(v, 1);
            v += __shfl_xor(v, 2);
            v += __shfl_xor(v, 4);
            v += __shfl_xor(v, 8);
            if (col16 == 0)
                atomicAdd(&S[mbase + s * 16 + quad * 4 + r], v);
        }
    }

    // fused tail: last block of this M-slice computes its 256 outputs
    __threadfence();                        // release S adds
    if (threadIdx.x == 0) {
        int c = atomicAdd(&flags[(17 + y) * 16], 1);
        iswin = (c == GEMM_X - 1);
    }
    __syncthreads();
    if (!iswin) return;
    __threadfence();                        // acquire other blocks' S adds

    {
        const int r  = y * 256 + threadIdx.x;       // one row per thread
        const int b  = r & (NBATCH - 1);
        const int t  = r >> 5;
        const int oi = b * TSTEPS + t;
        const int yv = yidx[oi];
        const float sv = agent_loadf(&S[r]);

        const ushort2* zr = reinterpret_cast<const ushort2*>(zsb + (long)r * EMBED);
        const float2*  wr = reinterpret_cast<const float2*>(Wv + (long)yv * EMBED);
        float acc = 0.f;
#pragma unroll
        for (int i = 0; i < 64; i++) {
            ushort2 z2 = zr[i];
            float2  w2 = wr[i];
            acc = fmaf(bf_raw2f(z2.x), w2.x, acc);
            acc = fmaf(bf_raw2f(z2.y), w2.y, acc);
        }
        // zsb holds z*log2e -> ln2*(acc - log2 S) + bv = z.Wv - ln S + bv
        out[oi] = LN2 * (acc - fast_log2(sv)) + bv[yv];
    }
}

// ---------------------------------------------------------------------------
extern "C" void kernel_launch(void* const* d_in, const int* in_sizes, int n_in,
                              void* d_out, int out_size, void* d_ws, size_t ws_size,
                              hipStream_t stream) {
    const int*   zi     = (const int*)d_in[0];
    const int*   y      = (const int*)d_in[1];
    const float* latent = (const float*)d_in[2];
    const float* Wt     = (const float*)d_in[3];
    const float* bt     = (const float*)d_in[4];
    const float* Wv     = (const float*)d_in[5];
    const float* bv     = (const float*)d_in[6];
    float* out = (float*)d_out;

    char* ws = (char*)d_ws;
    // workspace layout (~14.3 MB total):
    unsigned short* zsb   = (unsigned short*)ws;                       // 1 MB   @ 0
    float*          S     = (float*)(ws + (1u << 20));                 // 16 KB  @ 1M
    int*            flags = (int*)(ws + (1u << 20) + (16u << 10));     // 2.1 KB @ 1M+16K
    float*          ebt   = (float*)(ws + (1u << 20) + (64u << 10));   // 197 KB @ 1M+64K
    unsigned short* wvb   = (unsigned short*)(ws + (2u << 20));        // 12.28MB@ 2M

    // zero S + flags in one async memset (graph-capture safe)
    hipMemsetAsync(ws + (1u << 20), 0, (16u << 10) + FLAG_INTS * sizeof(int), stream);

    fused_kernel<<<NBLK, 256, 0, stream>>>(zi, y, latent, Wt, bt, Wv, bv,
                                           zsb, wvb, ebt, S, flags, out);
}

// Round 10
// 228.266 us; speedup vs baseline: 5.3569x; 5.3569x over previous
//
#include <hip/hip_runtime.h>
#include <hip/hip_bf16.h>

#define EMBED 128
#define TSTEPS 128
#define NBATCH 32
#define VDIM 50257
#define VPAD 50304            // 786 groups * 64 cols
#define MROWS 4096            // NBATCH * TSTEPS
#define NGROUPS 786           // VPAD / 64
#define GRIDX 128             // B-sweep split: 786 = 128*6 + 18
#define GRIDY 16              // 256-row M slices
#define CONV_N4 ((VDIM * EMBED) / 4)          // 1608224 float4 elements
#define CONV_BLOCKS ((CONV_N4 + 255) / 256)   // 6283

static constexpr float LOG2E = 1.4426950408889634f;
static constexpr float LN2   = 0.6931471805599453f;

__device__ __forceinline__ float fast_exp2(float x) {
#if __has_builtin(__builtin_amdgcn_exp2f)
    return __builtin_amdgcn_exp2f(x);
#else
    return exp2f(x);
#endif
}
__device__ __forceinline__ float fast_log2(float x) {
#if __has_builtin(__builtin_amdgcn_logf)
    return __builtin_amdgcn_logf(x);
#else
    return log2f(x);
#endif
}
__device__ __forceinline__ unsigned short f2bf_raw(float f) {
    __hip_bfloat16 h = __float2bfloat16(f);
    union { __hip_bfloat16 b; unsigned short u; } cvt;
    cvt.b = h;
    return cvt.u;
}
__device__ __forceinline__ float bf_raw2f(unsigned short u) {
    union { unsigned int u; float f; } cvt;
    cvt.u = ((unsigned int)u) << 16;
    return cvt.f;
}

// ---------------------------------------------------------------------------
// K0 (fused setup): blocks [0,32) = sequential scan (one batch chain each);
// blocks [32, 32+CONV_BLOCKS) convert Wv fp32->bf16 (+ zero pad rows), build
// ebt[j] = exp2(bv[j]*log2e) (pad -> 0), and zero S.
//
// Scan: e = tid>>1, h = tid&1; half-dots combine with one shfl_xor; z is
// ping-pong buffered, ONE __syncthreads per step; the per-step bf16 emission
// goes to a 32 KB LDS stash (lgkmcnt-only barrier drain — no global stores
// in the loop), bulk-stored coalesced at the end (R8-verified, absmax
// 0.125).  fp32 summation order ((zc+sA)+sB)+bt and libm tanhf are bit-exact
// vs rounds 1/3/5-8: the recurrence amplifies 1e-6/step approximations to
// ~0.2 absmax (round-4 failure) — do not perturb the trajectory.
//
// NOTE (round-9 lesson): do NOT try in-kernel producer-consumer overlap of
// scan and gemm — device-scope release/acquire fences on gfx950 force L2
// writeback/invalidate per fence; measured 5.6x regression (1222 us).
// ---------------------------------------------------------------------------
__global__ __launch_bounds__(256) void setup_kernel(const int* __restrict__ zi,
                                                    const float* __restrict__ latent,
                                                    const float* __restrict__ Wt,
                                                    const float* __restrict__ bt,
                                                    const float* __restrict__ Wv,
                                                    const float* __restrict__ bv,
                                                    unsigned short* __restrict__ zsb,
                                                    unsigned short* __restrict__ Wvb,
                                                    float* __restrict__ ebt,
                                                    float* __restrict__ S) {
    if (blockIdx.x >= NBATCH) {
        const int cb = blockIdx.x - NBATCH;
        if (cb == 0) {                      // zero the S accumulator
#pragma unroll
            for (int i = 0; i < MROWS / 256; i++)
                S[i * 256 + threadIdx.x] = 0.f;
        }
        if (cb == 1) {                      // zero bf16 pad rows of Wvb
            const int base4 = (VDIM * EMBED) / 4;
            const int npad4 = ((VPAD - VDIM) * EMBED) / 4;
            for (int i = threadIdx.x; i < npad4; i += 256)
                reinterpret_cast<ushort4*>(Wvb)[base4 + i] = make_ushort4(0, 0, 0, 0);
        }
        const int idx = cb * 256 + threadIdx.x;
        if (idx < VPAD)                     // ebt = e^bv (pad -> 0)
            ebt[idx] = (idx < VDIM) ? fast_exp2(bv[idx] * LOG2E) : 0.f;
        if (idx < CONV_N4) {
            float4 v = reinterpret_cast<const float4*>(Wv)[idx];
            ushort4 o;
            o.x = f2bf_raw(v.x); o.y = f2bf_raw(v.y);
            o.z = f2bf_raw(v.z); o.w = f2bf_raw(v.w);
            reinterpret_cast<ushort4*>(Wvb)[idx] = o;
        }
        return;
    }

    // ---- scan path: one block per batch element ----
    __shared__ float zbuf[2][EMBED];
    __shared__ unsigned short zstash[TSTEPS * EMBED];   // 32 KB bf16 stash
    const int b = blockIdx.x;
    const int e = threadIdx.x >> 1;     // output element 0..127
    const int h = threadIdx.x & 1;      // k-half

    // cache Wt[e][h*64 .. h*64+63] in registers (64 VGPRs)
    float4 wrow[16];
    const float4* wt4 = reinterpret_cast<const float4*>(Wt + e * EMBED + h * 64);
#pragma unroll
    for (int i = 0; i < 16; i++) wrow[i] = wt4[i];
    const float bte = bt[e];

    if (h == 0) zbuf[0][e] = latent[zi[b] * EMBED + e];
    __syncthreads();

    int cur = 0;
    for (int t = 0; t < TSTEPS; t++) {
        const float zc = zbuf[cur][e];      // lane pairs broadcast
        if (h == 0)                         // stash pre-update z (bf16 * log2e)
            zstash[t * EMBED + e] = f2bf_raw(zc * LOG2E);

        // half-dot over k in [h*64, h*64+64)
        const float4* z4 = reinterpret_cast<const float4*>(&zbuf[cur][h * 64]);
        float4 acc = {0.f, 0.f, 0.f, 0.f};
#pragma unroll
        for (int i = 0; i < 16; i++) {
            float4 zv = z4[i];
            acc.x += zv.x * wrow[i].x;
            acc.y += zv.y * wrow[i].y;
            acc.z += zv.z * wrow[i].z;
            acc.w += zv.w * wrow[i].w;
        }
        float v = acc.x + acc.y + acc.z + acc.w;
        float p = __shfl_xor(v, 1);         // partner half (same e, other h)
        float sA = h ? p : v;
        float sB = h ? v : p;
        // summation order identical to rounds 1/3/5 (bit-exact trajectory)
        float znew = tanhf(((zc + sA) + sB) + bte);   // exact libm tanh
        if (h == 0) zbuf[cur ^ 1][e] = znew;
        __syncthreads();                    // lgkmcnt-only drain (no stores)
        cur ^= 1;
    }

    // bulk store: 32 KB contiguous (rows b*128..b*128+127), coalesced b128
    uint4* dst = reinterpret_cast<uint4*>(zsb + (long)b * TSTEPS * EMBED);
    const uint4* src = reinterpret_cast<const uint4*>(zstash);
    for (int i = threadIdx.x; i < TSTEPS * EMBED / 8; i += 256)
        dst[i] = src[i];
}

// ---------------------------------------------------------------------------
// K1: fused GEMM + sum-of-exp2, LDS-staged B (double-buffered).
// A = zsb [4096 x 128] bf16 (prescaled by log2e), register-resident per wave.
// B = Wvb [VPAD x 128] bf16 (zero-padded).  Block: 4 waves x 64 rows = 256
// rows x 6-7 groups of 64 N-cols (GRIDX=128: round-10 — 2048 blocks keeps
// the 4-5 blocks/CU residency fed; the 1024-block grid was residency-limited
// with no backlog.  Round-8 showed bigger per-wave tiles kill occupancy —
// keep a[4][4] / VGPR ~100).  16 KB B-tiles DMAd to LDS via global_load_lds
// w=16 with XOR-16 granule swizzle (conflict-free ds_read_b128), double
// buffered, one barrier per group.  Bias factor ebt (= e^bv, pad 0) loaded
// directly from global per group — issued post-barrier, consumed at group
// end, no LDS stage.  Accumulators start from a shared zero quad; bias
// applied as sums = fma(exp2(d), ebt, sums).
// mfma_f32_16x16x32_bf16 layouts (HW-verified, guide §3):
//   A: lane holds A[m=lane&15][k=(lane>>4)*8 + j], j=0..7
//   B: lane holds B[n=lane&15][k=(lane>>4)*8 + j]
//   D: lane holds D[row=(lane>>4)*4 + r][col=lane&15], r=0..3
// ---------------------------------------------------------------------------
typedef __attribute__((ext_vector_type(8))) short bfrag;
typedef __attribute__((ext_vector_type(4))) float f32x4;

__global__ __launch_bounds__(256) void gemm_lse_kernel(const unsigned short* __restrict__ zsb,
                                                       const unsigned short* __restrict__ Wvb,
                                                       const float* __restrict__ ebt,
                                                       float* __restrict__ S) {
    __shared__ short ldsb[2][8192];          // 2 x 16 KB B tiles

    const int lane  = threadIdx.x & 63;
    const int wave  = threadIdx.x >> 6;
    const int col16 = lane & 15;
    const int quad  = lane >> 4;
    const int mbase = blockIdx.y * 256 + wave * 64;

    // group range for this x-block: 786 = 128*6 + 18
    const int x  = blockIdx.x;
    const int g0 = x * 6 + min(x, 18);
    const int g1 = g0 + 6 + (x < 18 ? 1 : 0);

    // A fragments: 4 M-subtiles x 4 K-chunks, register resident (64 VGPRs)
    bfrag a[4][4];
    const short* zss = reinterpret_cast<const short*>(zsb);
#pragma unroll
    for (int s = 0; s < 4; s++)
#pragma unroll
        for (int c = 0; c < 4; c++) {
            const short* p = zss + (long)(mbase + s * 16 + col16) * EMBED + c * 32 + quad * 8;
            a[s][c] = *reinterpret_cast<const bfrag*>(p);
        }

    float sums[16];
#pragma unroll
    for (int i = 0; i < 16; i++) sums[i] = 0.f;

    const short* wvs = reinterpret_cast<const short*>(Wvb);

    // stage group g's 16 KB B-tile into ldsb[buf] (swizzled, coalesced)
    auto stage = [&](int buf, int g) {
#pragma unroll
        for (int j = 0; j < 4; j++) {
            const int r   = (wave * 4 + j) * 4 + quad;
            const int swz = col16 ^ (r & 15);          // XOR-16 granule swizzle
            const short* gp = wvs + (long)(g * 64 + r) * EMBED + swz * 8;
            __builtin_amdgcn_global_load_lds(
                (const __attribute__((address_space(1))) void*)gp,
                (__attribute__((address_space(3))) void*)&ldsb[buf][(wave * 4 + j) * 512],
                16, 0, 0);
        }
    };

    int cur = 0;
    stage(0, g0);

    const f32x4 dzero = {0.f, 0.f, 0.f, 0.f};

    for (int g = g0; g < g1; g++) {
        __syncthreads();                     // buf[cur] staged; prev reads done
        if (g + 1 < g1) stage(cur ^ 1, g + 1);

        float ebl[4];                        // e^bias: issued early, used late
#pragma unroll
        for (int c = 0; c < 4; c++) ebl[c] = ebt[g * 64 + c * 16 + col16];

#pragma unroll
        for (int c = 0; c < 4; c++) {
            // fragment reads: logical (r = c*16+col16, kpart = kc*4+quad),
            // physical col = kpart ^ (r&15) = kpart ^ col16
            bfrag bf[4];
#pragma unroll
            for (int kc = 0; kc < 4; kc++)
                bf[kc] = *reinterpret_cast<const bfrag*>(
                    &ldsb[cur][(c * 16 + col16) * 128 + (((kc * 4 + quad) ^ col16) * 8)]);

            // kc-outer, s-inner: consecutive MFMAs are independent (4 chains)
            f32x4 d[4];
#pragma unroll
            for (int s = 0; s < 4; s++)
                d[s] = __builtin_amdgcn_mfma_f32_16x16x32_bf16(a[s][0], bf[0], dzero, 0, 0, 0);
#pragma unroll
            for (int kc = 1; kc < 4; kc++)
#pragma unroll
                for (int s = 0; s < 4; s++)
                    d[s] = __builtin_amdgcn_mfma_f32_16x16x32_bf16(a[s][kc], bf[kc], d[s], 0, 0, 0);

#pragma unroll
            for (int s = 0; s < 4; s++)
#pragma unroll
                for (int r = 0; r < 4; r++)
                    sums[s * 4 + r] = fmaf(fast_exp2(d[s][r]), ebl[c], sums[s * 4 + r]);
        }
        cur ^= 1;
    }

    // reduce partial sums over the 16 columns, one atomic per row per block
#pragma unroll
    for (int s = 0; s < 4; s++) {
#pragma unroll
        for (int r = 0; r < 4; r++) {
            float v = sums[s * 4 + r];
            v += __shfl_xor(v, 1);
            v += __shfl_xor(v, 2);
            v += __shfl_xor(v, 4);
            v += __shfl_xor(v, 8);
            if (col16 == 0)
                atomicAdd(&S[mbase + s * 16 + quad * 4 + r], v);
        }
    }
}

// ---------------------------------------------------------------------------
// K2: yp[row] = ln2*(dot_scaled - log2(S[row])) + bv[y[row]], where
// dot_scaled = (bf16 zsb row) . (fp32 Wv[y] row)  -- zsb is z*log2e in bf16;
// bf16 quantization adds only ~1e-3 to the target dot (budget 0.156).
// One wave per row; lane l handles elements {2l, 2l+1}.
// ---------------------------------------------------------------------------
__global__ __launch_bounds__(256) void tail_kernel(const unsigned short* __restrict__ zsb,
                                                   const float* __restrict__ Wv,
                                                   const float* __restrict__ bv,
                                                   const int* __restrict__ y,
                                                   const float* __restrict__ S,
                                                   float* __restrict__ out) {
    const int row  = blockIdx.x * 4 + (threadIdx.x >> 6);
    const int lane = threadIdx.x & 63;
    const int yv = y[row];
    const ushort2* zr = reinterpret_cast<const ushort2*>(zsb + (long)row * EMBED);
    const float2*  wr = reinterpret_cast<const float2*>(Wv + (long)yv * EMBED);
    ushort2 z2 = zr[lane];
    float2  w2 = wr[lane];
    float v = bf_raw2f(z2.x) * w2.x + bf_raw2f(z2.y) * w2.y;
    v += __shfl_xor(v, 32);
    v += __shfl_xor(v, 16);
    v += __shfl_xor(v, 8);
    v += __shfl_xor(v, 4);
    v += __shfl_xor(v, 2);
    v += __shfl_xor(v, 1);
    if (lane == 0)
        out[row] = LN2 * (v - fast_log2(S[row])) + bv[yv];
}

// ---------------------------------------------------------------------------
extern "C" void kernel_launch(void* const* d_in, const int* in_sizes, int n_in,
                              void* d_out, int out_size, void* d_ws, size_t ws_size,
                              hipStream_t stream) {
    const int*   zi     = (const int*)d_in[0];
    const int*   y      = (const int*)d_in[1];
    const float* latent = (const float*)d_in[2];
    const float* Wt     = (const float*)d_in[3];
    const float* bt     = (const float*)d_in[4];
    const float* Wv     = (const float*)d_in[5];
    const float* bv     = (const float*)d_in[6];
    float* out = (float*)d_out;

    char* ws = (char*)d_ws;
    // workspace layout (~14.3 MB total):
    unsigned short* zsb = (unsigned short*)ws;                         // 1 MB   @ 0
    float*          S   = (float*)(ws + (1u << 20));                   // 16 KB  @ 1M
    float*          ebt = (float*)(ws + (1u << 20) + (64u << 10));     // 197 KB @ 1M+64K
    unsigned short* wvb = (unsigned short*)(ws + (2u << 20));          // 12.28MB@ 2M

    setup_kernel<<<NBATCH + CONV_BLOCKS, 256, 0, stream>>>(zi, latent, Wt, bt, Wv, bv,
                                                           zsb, wvb, ebt, S);

    gemm_lse_kernel<<<dim3(GRIDX, GRIDY), 256, 0, stream>>>(zsb, wvb, ebt, S);

    tail_kernel<<<MROWS / 4, 256, 0, stream>>>(zsb, Wv, bv, y, S, out);
}